// Round 9
// baseline (64.610 us; speedup 1.0000x reference)
//
#include <hip/hip_runtime.h>
#include <hip/hip_bf16.h>

typedef unsigned int u32;
typedef unsigned short u16;
typedef unsigned long long u64;

#define BATCH 256
#define NN 4096
#define DIM 512

using short8 = __attribute__((ext_vector_type(8))) short;
using f32x4  = __attribute__((ext_vector_type(4))) float;

__device__ inline float b2f(u16 u){ u32 i = ((u32)u)<<16; float f; __builtin_memcpy(&f,&i,4); return f; }
__device__ inline u16 f2b(float v){ __hip_bfloat16 h = __float2bfloat16(v); u16 r; __builtin_memcpy(&r,&h,2); return r; }

__device__ inline float ldv(const void* p, size_t i, int isbf){
  return isbf ? b2f(((const u16*)p)[i]) : ((const float*)p)[i];
}
__device__ inline void stv(void* p, size_t i, float v, int isbf){
  if (isbf) ((__hip_bfloat16*)p)[i] = __float2bfloat16(v);
  else ((float*)p)[i] = v;
}

__device__ inline int sniff(const void* X, int t, int* sh){
  if (t < 64){
    u32 v = ((const u32*)X)[t];
    u16 lo = (u16)(v & 0xffffu);
    int e = (lo >> 7) & 0xff;
    int sane = ((lo & 0x7fffu) == 0) || (e >= 110 && e <= 132);
    u64 m = __ballot(sane);
    if (t == 0) *sh = (__popcll(m) >= 32) ? 1 : 0;
  }
  __syncthreads();
  return *sh;
}

// K1: self-sufficient score. 256 blocks x 256 thr (r3 tile: wave 32b x 32n, 2x2).
// w2 folded into the MFMA K-loop (zero extra traffic, r6-verified numerics);
// race-free pack2 partial writes (no init dependency, r5-verified);
// blocks 0..31 build XT via the r8-verified coalesced LDS transpose AFTER score.
__global__ __launch_bounds__(256) void k1_score(const void* X, const void* W,
    u16* Xb, u16* Wb, u16* XT, u64* pack2){
  __shared__ int sflag;
  __shared__ float sval[4][32];
  __shared__ int   sidx[4][32];
  __shared__ u32 sT[64][33];
  int t = threadIdx.x;
  int isbf = sniff(X, t, &sflag);
  int wv = t>>6, l = t&63, lr = l&15, lg = l>>4;

  int id = blockIdx.x;                 // XCD-grouped decode (r3 verbatim)
  int xcd = id & 7, sub = id >> 3;
  int ny = xcd*4 + (sub>>3);           // n-chunk 0..31 (4 per XCD)
  int bx = sub & 7;                    // b-tile 0..7
  int b0 = bx*32;
  int n0 = ny*128 + wv*32;

  if (!isbf){                          // f32 fallback: block-local converts
    for (int i=t; i<32*DIM; i+=256){
      size_t gi = (size_t)(b0 + (i>>9))*DIM + (i&511);
      Xb[gi] = f2b(((const float*)X)[gi]);
    }
    for (int i=t; i<128*DIM; i+=256){  // own chunk (benign same-value overlap)
      size_t gi = (size_t)(ny*128 + (i>>9))*DIM + (i&511);
      Wb[gi] = f2b(((const float*)W)[gi]);
    }
    __syncthreads();
  }
  const u16* Xp = isbf ? (const u16*)X : Xb;
  const u16* Wp = isbf ? (const u16*)W : Wb;

  const u16* xp0 = Xp + (size_t)(b0 + lr)*DIM + lg*8;
  const u16* xp1 = xp0 + (size_t)16*DIM;
  const u16* wp0 = Wp + (size_t)(n0 + lr)*DIM + lg*8;
  const u16* wp1 = wp0 + (size_t)16*DIM;

  f32x4 acc00 = {0,0,0,0}, acc01 = {0,0,0,0}, acc10 = {0,0,0,0}, acc11 = {0,0,0,0};
  float sq0 = 0.f, sq1 = 0.f;          // ||W row||^2 partials from same fragments
  #pragma unroll
  for (int ks=0; ks<16; ++ks){
    short8 a0 = *(const short8*)(xp0 + ks*32);
    short8 a1 = *(const short8*)(xp1 + ks*32);
    short8 w0 = *(const short8*)(wp0 + ks*32);
    short8 w1 = *(const short8*)(wp1 + ks*32);
    acc00 = __builtin_amdgcn_mfma_f32_16x16x32_bf16(a0, w0, acc00, 0,0,0);
    acc01 = __builtin_amdgcn_mfma_f32_16x16x32_bf16(a0, w1, acc01, 0,0,0);
    acc10 = __builtin_amdgcn_mfma_f32_16x16x32_bf16(a1, w0, acc10, 0,0,0);
    acc11 = __builtin_amdgcn_mfma_f32_16x16x32_bf16(a1, w1, acc11, 0,0,0);
    #pragma unroll
    for (int q=0;q<8;++q){
      float f0 = b2f((u16)w0[q]); sq0 = fmaf(f0, f0, sq0);
      float f1 = b2f((u16)w1[q]); sq1 = fmaf(f1, f1, sq1);
    }
  }
  // lane (lr,lg): squares over k ≡ lg*8 (mod 32); xor over lg bits -> full row sums
  sq0 += __shfl_xor(sq0, 16); sq0 += __shfl_xor(sq0, 32);
  sq1 += __shfl_xor(sq1, 16); sq1 += __shfl_xor(sq1, 32);

  #pragma unroll
  for (int bb=0; bb<2; ++bb){
    #pragma unroll
    for (int r=0;r<4;++r){
      float s0 = sq0 - 2.f*(bb ? acc10[r] : acc00[r]);
      float s1 = sq1 - 2.f*(bb ? acc11[r] : acc01[r]);
      float bv; int bi;
      if (s0 <= s1){ bv = s0; bi = n0 + lr; } else { bv = s1; bi = n0 + 16 + lr; }
      #pragma unroll
      for (int m=1; m<16; m<<=1){
        float ov = __shfl_xor(bv, m);
        int   oi = __shfl_xor(bi, m);
        if (ov < bv || (ov == bv && oi < bi)){ bv = ov; bi = oi; }
      }
      if (lr == 0){ int bl = bb*16 + lg*4 + r; sval[wv][bl] = bv; sidx[wv][bl] = bi; }
    }
  }
  __syncthreads();
  if (t < 32){                         // one write per (ny,b) slot; no atomics, no init
    float bv = sval[0][t]; int bi = sidx[0][t];
    #pragma unroll
    for (int w4=1; w4<4; ++w4){
      float ov = sval[w4][t]; int oi = sidx[w4][t];
      if (ov < bv || (ov == bv && oi < bi)){ bv = ov; bi = oi; }
    }
    u32 sb = __float_as_uint(bv);
    sb = (sb & 0x80000000u) ? ~sb : (sb | 0x80000000u);
    pack2[(size_t)ny*BATCH + b0 + t] = ((u64)sb << 32) | (u32)bi;
  }

  // ---- XT build (r8-verified coalesced 64x64 LDS transpose), blocks 0..31 ----
  if (id < 32){
    int td = id & 7, tb = id >> 3;     // d-tile 0..7, b-tile 0..3
    #pragma unroll
    for (int it=0; it<8; ++it){
      int i = it*256 + t;
      int r = i>>5, cc = i&31;
      size_t gi = (size_t)(tb*64 + r)*DIM + td*64 + cc*2;
      u32 v;
      if (isbf){
        v = *(const u32*)((const u16*)X + gi);
      } else {
        float2 f = *(const float2*)((const float*)X + gi);
        v = (u32)f2b(f.x) | ((u32)f2b(f.y) << 16);
      }
      sT[r][cc] = v;
    }
    __syncthreads();
    #pragma unroll
    for (int it=0; it<8; ++it){
      int i = it*256 + t;
      int dd = i>>5, bb2 = i&31;
      u32 lo = sT[bb2*2][dd>>1], hi = sT[bb2*2+1][dd>>1];
      int sh = (dd&1)*16;
      u32 v = ((lo >> sh) & 0xffffu) | (((hi >> sh) & 0xffffu) << 16);
      *(u32*)(XT + (size_t)(td*64+dd)*BATCH + tb*64 + bb2*2) = v;
    }
  }
}

// K2: pack2 reduce (r5-verified) -> bmu -> h tile -> MFMA hX -> fused update.
// 256 blocks x 512 threads; block owns 16 n rows; wave wv covers d in [wv*64,+64).
__global__ __launch_bounds__(512) void k2_update(const void* X, const u16* XT, const void* W,
    const u64* pack2, const int* passo, const int* total, void* out){
  __shared__ int sflag;
  __shared__ u64 smin[512];
  __shared__ int sbmu[256];
  __shared__ u16 hT[16][264];
  __shared__ float hpart[8][8];
  __shared__ float hs[16];
  int t = threadIdx.x;
  int isbf = sniff(X, t, &sflag);
  int wv = t>>6, l = t&63, lr = l&15, lg = l>>4;
  int n0 = blockIdx.x * 16;

  // ---- final argmin across the 32 chunks (L2-broadcast reads) ----
  {
    int b = t & 255, half = t >> 8;
    u64 m = ~0ull;
    #pragma unroll
    for (int c=0;c<16;++c){
      u64 v = pack2[(size_t)(half*16 + c)*BATCH + b];
      if (v < m) m = v;
    }
    smin[t] = m;
  }
  __syncthreads();
  if (t < 256){
    u64 m = smin[t] < smin[t+256] ? smin[t] : smin[t+256];
    sbmu[t] = (int)(u32)(m & 0xffffffffu);
  }
  __syncthreads();

  float decay = expf(-(float)passo[0] / (float)total[0]);
  float taxa = 0.5f*decay, sigma = 32.f*decay;
  float inv2s2 = 1.f/(2.f*sigma*sigma);
  if (blockIdx.x == 0 && t == 0){
    stv(out, (size_t)NN*DIM,     taxa,  isbf);
    stv(out, (size_t)NN*DIM + 1, sigma, isbf);
  }

  // ---- h tile + row sums ----
  {
    int b = t & 255;
    int rbase = (t >> 8) * 8;
    int m = sbmu[b];
    int mx = m & 63, my = m >> 6;
    float hv[8];
    #pragma unroll
    for (int i=0;i<8;++i){
      int n = n0 + rbase + i;
      int dx = (n & 63) - mx;
      int dy = (n >> 6) - my;
      float h = expf(-(float)(dx*dx + dy*dy) * inv2s2);
      hv[i] = h;
      hT[rbase + i][b] = f2b(h);
    }
    #pragma unroll
    for (int i=0;i<8;++i){
      float s = hv[i];
      #pragma unroll
      for (int off=32; off; off>>=1) s += __shfl_down(s, off);
      if (l == 0) hpart[wv][i] = s;
    }
  }
  __syncthreads();
  if (t < 16){
    int g = (t >> 3) * 4;
    hs[t] = hpart[g][t&7] + hpart[g+1][t&7] + hpart[g+2][t&7] + hpart[g+3][t&7];
  }
  __syncthreads();

  // ---- MFMA hX + fused update ----
  int d0 = wv * 64;
  f32x4 acc[4];
  #pragma unroll
  for (int f=0;f<4;++f) acc[f] = (f32x4){0.f,0.f,0.f,0.f};

  #pragma unroll
  for (int ks=0; ks<8; ++ks){
    short8 a = *(const short8*)(&hT[lr][ks*32 + lg*8]);
    #pragma unroll
    for (int f=0; f<4; ++f){
      short8 bfr = *(const short8*)(XT + (size_t)(d0 + f*16 + lr)*BATCH + ks*32 + lg*8);
      acc[f] = __builtin_amdgcn_mfma_f32_16x16x32_bf16(a, bfr, acc[f], 0,0,0);
    }
  }

  float cc = taxa / (float)BATCH;
  #pragma unroll
  for (int r=0;r<4;++r){
    int n = n0 + lg*4 + r;
    float hsv = hs[lg*4 + r];
    #pragma unroll
    for (int f=0;f<4;++f){
      size_t gi = (size_t)n*DIM + d0 + f*16 + lr;
      float wv_ = ldv(W, gi, isbf);
      float o = wv_ + cc*(acc[f][r] - hsv*wv_);
      stv(out, gi, o, isbf);
    }
  }
}

extern "C" void kernel_launch(void* const* d_in, const int* in_sizes, int n_in,
                              void* d_out, int out_size, void* d_ws, size_t ws_size,
                              hipStream_t stream) {
  const void* X = d_in[0];      // (256, 512)
  const void* W = d_in[1];      // (4096, 512)
  // d_in[2] = localizacoes — recomputed on device as (n%64, n/64)
  const int* passo = (const int*)d_in[3];
  const int* total = (const int*)d_in[4];

  char* ws = (char*)d_ws;
  u64* pack2 = (u64*)(ws + 0);          // 32*256*8 = 65536
  u16* XT    = (u16*)(ws + 65536);      // 512*256*2 = 262144
  u16* Xb    = (u16*)(ws + 327680);     // f32 fallback
  u16* Wb    = (u16*)(ws + 589824);     // f32 fallback (4 MiB)

  k1_score <<<256, 256, 0, stream>>>(X, W, Xb, Wb, XT, pack2);
  k2_update<<<256, 512, 0, stream>>>(X, XT, W, pack2, passo, total, d_out);
}

// Round 10
// 64.455 us; speedup vs baseline: 1.0024x; 1.0024x over previous
//
#include <hip/hip_runtime.h>
#include <hip/hip_bf16.h>

typedef unsigned int u32;
typedef unsigned short u16;
typedef unsigned long long u64;

#define BATCH 256
#define NN 4096
#define DIM 512

using short8 = __attribute__((ext_vector_type(8))) short;
using f32x4  = __attribute__((ext_vector_type(4))) float;

__device__ inline float b2f(u16 u){ u32 i = ((u32)u)<<16; float f; __builtin_memcpy(&f,&i,4); return f; }
__device__ inline u16 f2b(float v){ __hip_bfloat16 h = __float2bfloat16(v); u16 r; __builtin_memcpy(&r,&h,2); return r; }

__device__ inline float ldv(const void* p, size_t i, int isbf){
  return isbf ? b2f(((const u16*)p)[i]) : ((const float*)p)[i];
}
__device__ inline void stv(void* p, size_t i, float v, int isbf){
  if (isbf) ((__hip_bfloat16*)p)[i] = __float2bfloat16(v);
  else ((float*)p)[i] = v;
}

__device__ inline int sniff(const void* X, int t, int* sh){
  if (t < 64){
    u32 v = ((const u32*)X)[t];
    u16 lo = (u16)(v & 0xffffu);
    int e = (lo >> 7) & 0xff;
    int sane = ((lo & 0x7fffu) == 0) || (e >= 110 && e <= 132);
    u64 m = __ballot(sane);
    if (t == 0) *sh = (__popcll(m) >= 32) ? 1 : 0;
  }
  __syncthreads();
  return *sh;
}

// K1: cooperative-prewarm + XT transpose + MFMA score (w2 folded) -> pack2.
// 256 blocks x 256 thr, XCD-grouped (r3 decode). Prewarm: each block streams a
// DISJOINT 16-row slice of W (4MB collectively, once, coalesced) concurrently --
// restores the L3-warm W that r3's separate prep provided (r9 post-mortem:
// cold-W fragment loads run at ~200 GB/s => 70us).
__global__ __launch_bounds__(256) void k1_score(const void* X, const void* W,
    u16* Xb, u16* Wb, u16* XT, u64* pack2){
  __shared__ int sflag;
  __shared__ float sval[4][32];
  __shared__ int   sidx[4][32];
  __shared__ u32 sT[64][33];
  int t = threadIdx.x;
  int isbf = sniff(X, t, &sflag);
  int wv = t>>6, l = t&63, lr = l&15, lg = l>>4;

  int id = blockIdx.x;
  int xcd = id & 7, sub = id >> 3;
  int ny = xcd*4 + (sub>>3);           // n-chunk 0..31 (4 per XCD)
  int bx = sub & 7;                    // b-tile 0..7
  int b0 = bx*32;
  int nbase = ny*128;
  int n0 = nbase + wv*32;

  if (!isbf){                          // f32 fallback: converts double as prewarm
    for (int i=t; i<32*DIM; i+=256){
      size_t gi = (size_t)(b0 + (i>>9))*DIM + (i&511);
      Xb[gi] = f2b(((const float*)X)[gi]);
    }
    for (int i=t; i<128*DIM; i+=256){
      size_t gi = (size_t)(nbase + (i>>9))*DIM + (i&511);
      Wb[gi] = f2b(((const float*)W)[gi]);
    }
    __syncthreads();
  } else {
    // ---- W prewarm: disjoint 16-row slice, fully coalesced, keep-alive ----
    int pre0 = nbase + bx*16;
    const u16* wp = (const u16*)W + (size_t)(pre0 + (t>>4))*DIM + (t&15)*32;
    float s = 0.f;
    #pragma unroll
    for (int j=0;j<4;++j){
      short8 x = *(const short8*)(wp + j*8);
      #pragma unroll
      for (int q=0;q<8;++q){ float f = b2f((u16)x[q]); s += f*f; }
    }
    asm volatile("" :: "v"(s));        // keep loads live (rule 17)
  }

  // ---- XT transpose (r8-verified), tile = id&31, 8x redundant, uniform ----
  {
    int tile = id & 31;
    int td = tile & 7, tb = tile >> 3;
    #pragma unroll
    for (int it=0; it<8; ++it){
      int i = it*256 + t;
      int r = i>>5, cc = i&31;
      size_t gi = (size_t)(tb*64 + r)*DIM + td*64 + cc*2;
      u32 v;
      if (isbf){
        v = *(const u32*)((const u16*)X + gi);
      } else {
        float2 f = *(const float2*)((const float*)X + gi);
        v = (u32)f2b(f.x) | ((u32)f2b(f.y) << 16);
      }
      sT[r][cc] = v;
    }
    __syncthreads();
    #pragma unroll
    for (int it=0; it<8; ++it){
      int i = it*256 + t;
      int dd = i>>5, bb2 = i&31;
      u32 lo = sT[bb2*2][dd>>1], hi = sT[bb2*2+1][dd>>1];
      int sh = (dd&1)*16;
      u32 v = ((lo >> sh) & 0xffffu) | (((hi >> sh) & 0xffffu) << 16);
      *(u32*)(XT + (size_t)(td*64+dd)*BATCH + tb*64 + bb2*2) = v;
    }
  }

  // ---- MFMA score, w2 folded from same fragments (r9-verified numerics) ----
  const u16* Xp = isbf ? (const u16*)X : Xb;
  const u16* Wp = isbf ? (const u16*)W : Wb;
  const u16* xp0 = Xp + (size_t)(b0 + lr)*DIM + lg*8;
  const u16* xp1 = xp0 + (size_t)16*DIM;
  const u16* wp0 = Wp + (size_t)(n0 + lr)*DIM + lg*8;
  const u16* wp1 = wp0 + (size_t)16*DIM;

  f32x4 acc00 = {0,0,0,0}, acc01 = {0,0,0,0}, acc10 = {0,0,0,0}, acc11 = {0,0,0,0};
  float sq0 = 0.f, sq1 = 0.f;
  #pragma unroll
  for (int ks=0; ks<16; ++ks){
    short8 a0 = *(const short8*)(xp0 + ks*32);
    short8 a1 = *(const short8*)(xp1 + ks*32);
    short8 w0 = *(const short8*)(wp0 + ks*32);
    short8 w1 = *(const short8*)(wp1 + ks*32);
    acc00 = __builtin_amdgcn_mfma_f32_16x16x32_bf16(a0, w0, acc00, 0,0,0);
    acc01 = __builtin_amdgcn_mfma_f32_16x16x32_bf16(a0, w1, acc01, 0,0,0);
    acc10 = __builtin_amdgcn_mfma_f32_16x16x32_bf16(a1, w0, acc10, 0,0,0);
    acc11 = __builtin_amdgcn_mfma_f32_16x16x32_bf16(a1, w1, acc11, 0,0,0);
    #pragma unroll
    for (int q=0;q<8;++q){
      float f0 = b2f((u16)w0[q]); sq0 = fmaf(f0, f0, sq0);
      float f1 = b2f((u16)w1[q]); sq1 = fmaf(f1, f1, sq1);
    }
  }
  sq0 += __shfl_xor(sq0, 16); sq0 += __shfl_xor(sq0, 32);
  sq1 += __shfl_xor(sq1, 16); sq1 += __shfl_xor(sq1, 32);

  #pragma unroll
  for (int bb=0; bb<2; ++bb){
    #pragma unroll
    for (int r=0;r<4;++r){
      float s0 = sq0 - 2.f*(bb ? acc10[r] : acc00[r]);
      float s1 = sq1 - 2.f*(bb ? acc11[r] : acc01[r]);
      float bv; int bi;
      if (s0 <= s1){ bv = s0; bi = n0 + lr; } else { bv = s1; bi = n0 + 16 + lr; }
      #pragma unroll
      for (int m=1; m<16; m<<=1){
        float ov = __shfl_xor(bv, m);
        int   oi = __shfl_xor(bi, m);
        if (ov < bv || (ov == bv && oi < bi)){ bv = ov; bi = oi; }
      }
      if (lr == 0){ int bl = bb*16 + lg*4 + r; sval[wv][bl] = bv; sidx[wv][bl] = bi; }
    }
  }
  __syncthreads();
  if (t < 32){                         // one write per (ny,b) slot; race-free
    float bv = sval[0][t]; int bi = sidx[0][t];
    #pragma unroll
    for (int w4=1; w4<4; ++w4){
      float ov = sval[w4][t]; int oi = sidx[w4][t];
      if (ov < bv || (ov == bv && oi < bi)){ bv = ov; bi = oi; }
    }
    u32 sb = __float_as_uint(bv);
    sb = (sb & 0x80000000u) ? ~sb : (sb | 0x80000000u);
    pack2[(size_t)ny*BATCH + b0 + t] = ((u64)sb << 32) | (u32)bi;
  }
}

// K2 (r9 verbatim): pack2 reduce -> bmu -> h tile -> MFMA hX -> fused update.
__global__ __launch_bounds__(512) void k2_update(const void* X, const u16* XT, const void* W,
    const u64* pack2, const int* passo, const int* total, void* out){
  __shared__ int sflag;
  __shared__ u64 smin[512];
  __shared__ int sbmu[256];
  __shared__ u16 hT[16][264];
  __shared__ float hpart[8][8];
  __shared__ float hs[16];
  int t = threadIdx.x;
  int isbf = sniff(X, t, &sflag);
  int wv = t>>6, l = t&63, lr = l&15, lg = l>>4;
  int n0 = blockIdx.x * 16;

  {
    int b = t & 255, half = t >> 8;
    u64 m = ~0ull;
    #pragma unroll
    for (int c=0;c<16;++c){
      u64 v = pack2[(size_t)(half*16 + c)*BATCH + b];
      if (v < m) m = v;
    }
    smin[t] = m;
  }
  __syncthreads();
  if (t < 256){
    u64 m = smin[t] < smin[t+256] ? smin[t] : smin[t+256];
    sbmu[t] = (int)(u32)(m & 0xffffffffu);
  }
  __syncthreads();

  float decay = expf(-(float)passo[0] / (float)total[0]);
  float taxa = 0.5f*decay, sigma = 32.f*decay;
  float inv2s2 = 1.f/(2.f*sigma*sigma);
  if (blockIdx.x == 0 && t == 0){
    stv(out, (size_t)NN*DIM,     taxa,  isbf);
    stv(out, (size_t)NN*DIM + 1, sigma, isbf);
  }

  {
    int b = t & 255;
    int rbase = (t >> 8) * 8;
    int m = sbmu[b];
    int mx = m & 63, my = m >> 6;
    float hv[8];
    #pragma unroll
    for (int i=0;i<8;++i){
      int n = n0 + rbase + i;
      int dx = (n & 63) - mx;
      int dy = (n >> 6) - my;
      float h = expf(-(float)(dx*dx + dy*dy) * inv2s2);
      hv[i] = h;
      hT[rbase + i][b] = f2b(h);
    }
    #pragma unroll
    for (int i=0;i<8;++i){
      float s = hv[i];
      #pragma unroll
      for (int off=32; off; off>>=1) s += __shfl_down(s, off);
      if (l == 0) hpart[wv][i] = s;
    }
  }
  __syncthreads();
  if (t < 16){
    int g = (t >> 3) * 4;
    hs[t] = hpart[g][t&7] + hpart[g+1][t&7] + hpart[g+2][t&7] + hpart[g+3][t&7];
  }
  __syncthreads();

  int d0 = wv * 64;
  f32x4 acc[4];
  #pragma unroll
  for (int f=0;f<4;++f) acc[f] = (f32x4){0.f,0.f,0.f,0.f};

  #pragma unroll
  for (int ks=0; ks<8; ++ks){
    short8 a = *(const short8*)(&hT[lr][ks*32 + lg*8]);
    #pragma unroll
    for (int f=0; f<4; ++f){
      short8 bfr = *(const short8*)(XT + (size_t)(d0 + f*16 + lr)*BATCH + ks*32 + lg*8);
      acc[f] = __builtin_amdgcn_mfma_f32_16x16x32_bf16(a, bfr, acc[f], 0,0,0);
    }
  }

  float cc = taxa / (float)BATCH;
  #pragma unroll
  for (int r=0;r<4;++r){
    int n = n0 + lg*4 + r;
    float hsv = hs[lg*4 + r];
    #pragma unroll
    for (int f=0;f<4;++f){
      size_t gi = (size_t)n*DIM + d0 + f*16 + lr;
      float wv_ = ldv(W, gi, isbf);
      float o = wv_ + cc*(acc[f][r] - hsv*wv_);
      stv(out, gi, o, isbf);
    }
  }
}

extern "C" void kernel_launch(void* const* d_in, const int* in_sizes, int n_in,
                              void* d_out, int out_size, void* d_ws, size_t ws_size,
                              hipStream_t stream) {
  const void* X = d_in[0];      // (256, 512)
  const void* W = d_in[1];      // (4096, 512)
  // d_in[2] = localizacoes — recomputed on device as (n%64, n/64)
  const int* passo = (const int*)d_in[3];
  const int* total = (const int*)d_in[4];

  char* ws = (char*)d_ws;
  u64* pack2 = (u64*)(ws + 0);          // 32*256*8 = 65536
  u16* XT    = (u16*)(ws + 65536);      // 512*256*2 = 262144
  u16* Xb    = (u16*)(ws + 327680);     // f32 fallback
  u16* Wb    = (u16*)(ws + 589824);     // f32 fallback (4 MiB)

  k1_score <<<256, 256, 0, stream>>>(X, W, Xb, Wb, XT, pack2);
  k2_update<<<256, 512, 0, stream>>>(X, XT, W, pack2, passo, total, d_out);
}

// Round 11
// 43.067 us; speedup vs baseline: 1.5002x; 1.4966x over previous
//
#include <hip/hip_runtime.h>
#include <hip/hip_bf16.h>

typedef unsigned int u32;
typedef unsigned short u16;
typedef unsigned long long u64;

#define BATCH 256
#define NN 4096
#define DIM 512

using short8 = __attribute__((ext_vector_type(8))) short;
using f32x4  = __attribute__((ext_vector_type(4))) float;

__device__ inline float b2f(u16 u){ u32 i = ((u32)u)<<16; float f; __builtin_memcpy(&f,&i,4); return f; }
__device__ inline u16 f2b(float v){ __hip_bfloat16 h = __float2bfloat16(v); u16 r; __builtin_memcpy(&r,&h,2); return r; }

__device__ inline float ldv(const void* p, size_t i, int isbf){
  return isbf ? b2f(((const u16*)p)[i]) : ((const float*)p)[i];
}
__device__ inline void stv(void* p, size_t i, float v, int isbf){
  if (isbf) ((__hip_bfloat16*)p)[i] = __float2bfloat16(v);
  else ((float*)p)[i] = v;
}

__device__ inline int sniff(const void* X, int t, int* sh){
  if (t < 64){
    u32 v = ((const u32*)X)[t];
    u16 lo = (u16)(v & 0xffffu);
    int e = (lo >> 7) & 0xff;
    int sane = ((lo & 0x7fffu) == 0) || (e >= 110 && e <= 132);
    u64 m = __ballot(sane);
    if (t == 0) *sh = (__popcll(m) >= 32) ? 1 : 0;
  }
  __syncthreads();
  return *sh;
}

// K_prep (r8 verbatim): blocks 0..31 XT coalesced transpose (+Xb convert);
// blocks 32..543 w2 stream = the W PREFETCH pass (+Wb convert); block 32 inits pack.
__global__ __launch_bounds__(256) void k_prep(const void* X, const void* W,
    u64* pack, float* w2, u16* XT, u16* Xb, u16* Wb,
    const int* passo, const int* total, void* out){
  __shared__ int sflag;
  __shared__ u32 sT[64][33];
  int t = threadIdx.x;
  int isbf = sniff(X, t, &sflag);
  int blk = blockIdx.x;
  if (blk < 32){
    int td = blk & 7, tb = blk >> 3;
    #pragma unroll
    for (int it=0; it<8; ++it){
      int i = it*256 + t;
      int r = i>>5, cc = i&31;
      size_t gi = (size_t)(tb*64 + r)*DIM + td*64 + cc*2;
      u32 v;
      if (isbf){
        v = *(const u32*)((const u16*)X + gi);
      } else {
        float2 f = *(const float2*)((const float*)X + gi);
        v = (u32)f2b(f.x) | ((u32)f2b(f.y) << 16);
        *(u32*)(Xb + gi) = v;
      }
      sT[r][cc] = v;
    }
    __syncthreads();
    #pragma unroll
    for (int it=0; it<8; ++it){
      int i = it*256 + t;
      int dd = i>>5, bb2 = i&31;
      u32 lo = sT[bb2*2][dd>>1], hi = sT[bb2*2+1][dd>>1];
      int sh = (dd&1)*16;
      u32 v = ((lo >> sh) & 0xffffu) | (((hi >> sh) & 0xffffu) << 16);
      *(u32*)(XT + (size_t)(td*64+dd)*BATCH + tb*64 + bb2*2) = v;
    }
  } else {
    int j = blk - 32;
    int n0 = j*8;
    int wv = t>>6, lane = t&63;
    #pragma unroll
    for (int rr=0; rr<2; ++rr){
      int n = n0 + wv*2 + rr;
      float xv[8]; float s = 0.f;
      if (isbf){
        short8 x = *(const short8*)((const u16*)W + (size_t)n*DIM + lane*8);
        #pragma unroll
        for (int q=0;q<8;q++) xv[q] = b2f((u16)x[q]);
      } else {
        #pragma unroll
        for (int q=0;q<8;q++) xv[q] = ((const float*)W)[(size_t)n*DIM + lane*8 + q];
      }
      #pragma unroll
      for (int q=0;q<8;q++) s += xv[q]*xv[q];
      #pragma unroll
      for (int off=32; off; off>>=1) s += __shfl_down(s, off);
      if (lane == 0) w2[n] = s;
      if (!isbf){
        #pragma unroll
        for (int q=0;q<8;q++) Wb[(size_t)n*DIM + lane*8 + q] = f2b(xv[q]);
      }
    }
    if (j == 0){
      pack[t] = ~0ull;
      if (t == 0){
        float decay = expf(-(float)passo[0]/(float)total[0]);
        stv(out, (size_t)NN*DIM,     0.5f*decay, isbf);
        stv(out, (size_t)NN*DIM + 1, 32.f*decay, isbf);
      }
    }
  }
}

// K_score: 512 blocks x 512 thr = 16 waves/CU (4x r3's latency hiding).
// Block = 32b x 64n; 8 waves = 2 b-halves x 2 n-halves x 2 K-HALVES.
// kh=1 waves deposit partial acc/sq in LDS; kh=0 waves combine + argmin.
// w2 folded in-loop (r9-verified). XCD-grouped: 8 blocks sharing a 64-row
// W chunk land on one XCD.
__global__ __launch_bounds__(512) void k_score(const void* X, const void* W,
    const u16* Xws, const u16* Wws, u64* pack){
  __shared__ int sflag;
  __shared__ float pf[4][64][10];   // kh=1 partials: acc0[4], acc1[4], sq0, sq1
  __shared__ float sval[2][32];
  __shared__ int   sidx[2][32];
  int t = threadIdx.x;
  int isbf = sniff(X, t, &sflag);
  const u16* Xp = isbf ? (const u16*)X : Xws;
  const u16* Wp = isbf ? (const u16*)W : Wws;
  int wv = t>>6, l = t&63, lr = l&15, lg = l>>4;
  int bh = wv&1, nh = (wv>>1)&1, kh = wv>>2;

  int id = blockIdx.x;
  int xcd = id & 7, sub = id >> 3;       // 64 blocks per XCD
  int nc = xcd*8 + (sub>>3);             // n-chunk 0..63 (64 n rows each)
  int bt = sub & 7;                      // b-tile 0..7 (32 b each)
  int b0 = bt*32 + bh*16;
  int n0 = nc*64 + nh*32;
  int k0 = kh*256;

  const u16* xp  = Xp + (size_t)(b0 + lr)*DIM + k0 + lg*8;
  const u16* wp0 = Wp + (size_t)(n0 + lr)*DIM + k0 + lg*8;
  const u16* wp1 = wp0 + (size_t)16*DIM;

  f32x4 acc0 = {0,0,0,0}, acc1 = {0,0,0,0};
  float sq0 = 0.f, sq1 = 0.f;
  #pragma unroll
  for (int ks=0; ks<8; ++ks){
    short8 a  = *(const short8*)(xp  + ks*32);
    short8 w0 = *(const short8*)(wp0 + ks*32);
    short8 w1 = *(const short8*)(wp1 + ks*32);
    acc0 = __builtin_amdgcn_mfma_f32_16x16x32_bf16(a, w0, acc0, 0,0,0);
    acc1 = __builtin_amdgcn_mfma_f32_16x16x32_bf16(a, w1, acc1, 0,0,0);
    #pragma unroll
    for (int q=0;q<8;++q){
      float f0 = b2f((u16)w0[q]); sq0 = fmaf(f0, f0, sq0);
      float f1 = b2f((u16)w1[q]); sq1 = fmaf(f1, f1, sq1);
    }
  }
  // fold lg groups -> per-lr full K-half row sums
  sq0 += __shfl_xor(sq0, 16); sq0 += __shfl_xor(sq0, 32);
  sq1 += __shfl_xor(sq1, 16); sq1 += __shfl_xor(sq1, 32);

  if (kh){                               // deposit K-half-1 partials
    #pragma unroll
    for (int r=0;r<4;++r){ pf[wv-4][l][r] = acc0[r]; pf[wv-4][l][4+r] = acc1[r]; }
    pf[wv-4][l][8] = sq0; pf[wv-4][l][9] = sq1;
  }
  __syncthreads();
  if (!kh){                              // combine + argmin (per-wave-uniform branch)
    #pragma unroll
    for (int r=0;r<4;++r){ acc0[r] += pf[wv][l][r]; acc1[r] += pf[wv][l][4+r]; }
    sq0 += pf[wv][l][8]; sq1 += pf[wv][l][9];
    #pragma unroll
    for (int r=0;r<4;++r){
      float s0 = sq0 - 2.f*acc0[r];
      float s1 = sq1 - 2.f*acc1[r];
      float bv; int bi;
      if (s0 <= s1){ bv = s0; bi = n0 + lr; } else { bv = s1; bi = n0 + 16 + lr; }
      #pragma unroll
      for (int m=1; m<16; m<<=1){
        float ov = __shfl_xor(bv, m);
        int   oi = __shfl_xor(bi, m);
        if (ov < bv || (ov == bv && oi < bi)){ bv = ov; bi = oi; }
      }
      if (lr == 0){
        sval[nh][bh*16 + lg*4 + r] = bv;
        sidx[nh][bh*16 + lg*4 + r] = bi;
      }
    }
  }
  __syncthreads();
  if (t < 32){                           // combine n-halves -> 32 atomics/block
    float bv = sval[0][t]; int bi = sidx[0][t];
    float ov = sval[1][t]; int oi = sidx[1][t];
    if (ov < bv || (ov == bv && oi < bi)){ bv = ov; bi = oi; }
    u32 sb = __float_as_uint(bv);
    sb = (sb & 0x80000000u) ? ~sb : (sb | 0x80000000u);
    atomicMin(pack + bt*32 + t, ((u64)sb << 32) | (u32)bi);
  }
}

// K_update (r8 verbatim): h tile -> MFMA hX -> fused SOM update.
__global__ __launch_bounds__(512) void k_update(const void* X, const u16* XT, const void* W,
    const u64* pack, const int* passo, const int* total, void* out){
  __shared__ int sflag;
  __shared__ u16 hT[16][264];
  __shared__ float hpart[8][8];
  __shared__ float hs[16];
  int t = threadIdx.x;
  int isbf = sniff(X, t, &sflag);
  int wv = t>>6, l = t&63;
  int n0 = blockIdx.x * 16;

  float decay = expf(-(float)passo[0] / (float)total[0]);
  float taxa = 0.5f*decay, sigma = 32.f*decay;
  float inv2s2 = 1.f/(2.f*sigma*sigma);

  {
    int b = t & 255;
    int rbase = (t >> 8) * 8;
    int m = (int)(u32)(pack[b] & 0xffffffffu);
    int mx = m & 63, my = m >> 6;
    float hv[8];
    #pragma unroll
    for (int i=0;i<8;++i){
      int n = n0 + rbase + i;
      int dx = (n & 63) - mx;
      int dy = (n >> 6) - my;
      float h = expf(-(float)(dx*dx + dy*dy) * inv2s2);
      hv[i] = h;
      hT[rbase + i][b] = f2b(h);
    }
    #pragma unroll
    for (int i=0;i<8;++i){
      float s = hv[i];
      #pragma unroll
      for (int off=32; off; off>>=1) s += __shfl_down(s, off);
      if (l == 0) hpart[wv][i] = s;
    }
  }
  __syncthreads();
  if (t < 16){
    int g = (t >> 3) * 4;
    hs[t] = hpart[g][t&7] + hpart[g+1][t&7] + hpart[g+2][t&7] + hpart[g+3][t&7];
  }
  __syncthreads();

  int lr = l & 15, lg = l >> 4;
  int d0 = wv * 64;
  f32x4 acc[4];
  #pragma unroll
  for (int f=0;f<4;++f) acc[f] = (f32x4){0.f,0.f,0.f,0.f};

  #pragma unroll
  for (int ks=0; ks<8; ++ks){
    short8 a = *(const short8*)(&hT[lr][ks*32 + lg*8]);
    #pragma unroll
    for (int f=0; f<4; ++f){
      short8 bfr = *(const short8*)(XT + (size_t)(d0 + f*16 + lr)*BATCH + ks*32 + lg*8);
      acc[f] = __builtin_amdgcn_mfma_f32_16x16x32_bf16(a, bfr, acc[f], 0,0,0);
    }
  }

  float cc = taxa / (float)BATCH;
  #pragma unroll
  for (int r=0;r<4;++r){
    int n = n0 + lg*4 + r;
    float hsv = hs[lg*4 + r];
    #pragma unroll
    for (int f=0;f<4;++f){
      size_t gi = (size_t)n*DIM + d0 + f*16 + lr;
      float wv_ = ldv(W, gi, isbf);
      float o = wv_ + cc*(acc[f][r] - hsv*wv_);
      stv(out, gi, o, isbf);
    }
  }
}

extern "C" void kernel_launch(void* const* d_in, const int* in_sizes, int n_in,
                              void* d_out, int out_size, void* d_ws, size_t ws_size,
                              hipStream_t stream) {
  const void* X = d_in[0];      // (256, 512)
  const void* W = d_in[1];      // (4096, 512)
  // d_in[2] = localizacoes — recomputed on device as (n%64, n/64)
  const int* passo = (const int*)d_in[3];
  const int* total = (const int*)d_in[4];

  char* ws = (char*)d_ws;
  u64* pack = (u64*)(ws + 256);
  float* w2 = (float*)(ws + 2304);
  u16* XT   = (u16*)(ws + 18688);
  u16* Xb   = (u16*)(ws + 280832);
  u16* Wb   = (u16*)(ws + 542976);

  k_prep  <<<544, 256, 0, stream>>>(X, W, pack, w2, XT, Xb, Wb, passo, total, d_out);
  k_score <<<512, 512, 0, stream>>>(X, W, Xb, Wb, pack);
  k_update<<<256, 512, 0, stream>>>(X, XT, W, pack, passo, total, d_out);
}